// Round 1
// baseline (1186.794 us; speedup 1.0000x reference)
//
#include <hip/hip_runtime.h>

// VQ argmin: exact bit-level emulation of numpy fp32 reference:
//   A  = np.sum(flat*flat, axis=1)     (numpy pairwise-sum tree, fp32)
//   M2 = (2*flat) @ emb.T              (BLAS: sequential fp32 fma chain over d)
//   dist = (A - M2) + ee;  argmin_k (first-min ties)
// z_e_x: [B=16, D=256, H=64, W=64] fp32; embedding: [K=1024, D=256] fp32
// out: int32 [65536]
//
// R4: occupancy push. R3's LDS-free GEMV-broadcast structure kept (lanes->n,
// z coalesced + VGPR ping-pong, eT wave-uniform via s_load/SGPR, no LDS).
// Changes:
//  - NSPLIT 4->16 (KSPL=64=KT, NKT=1): grid 1024->4096 blocks so CUs hold
//    5 blocks (launch_bounds(256,5) caps VGPR at 102); z read once per split
//    (kt loop and z re-reads gone). Occupancy 45%->~60% to hide eT s_load /
//    z HBM latency that 4 waves/SIMD couldn't.
//  - cross-split combine via 64-bit lexicographic atomicMin on packed
//    (order-encoded dist bits << 32 | k): exact first-min ties, no pv/pk
//    arrays, no combine kernel.
//  - et transpose now LDS-tiled (both sides coalesced; was 256K scattered
//    4B stores).

#define D_DIM  256
#define K_DIM  1024
#define HW     4096
#define N_TOT  65536
#define NSPLIT 16
#define KSPL   (K_DIM / NSPLIT)   // 64 k's per split = acc regs per thread
#define F32MAX 3.402823466e38f

// ---- numpy pairwise_sum replication (n=256 = two 128-blocks of 8 accumulators)

__global__ void ee_kernel(const float* __restrict__ e, float* __restrict__ ee) {
#pragma clang fp contract(off)
    int k = blockIdx.x * blockDim.x + threadIdx.x;
    if (k >= K_DIM) return;
    const float* row = e + (size_t)k * D_DIM;
    float total = 0.0f;
    #pragma unroll
    for (int h = 0; h < 2; ++h) {
        const float* a = row + h * 128;
        float r[8];
        #pragma unroll
        for (int j = 0; j < 8; ++j) { float v = a[j]; r[j] = v * v; }
        #pragma unroll
        for (int i = 8; i < 128; i += 8) {
            #pragma unroll
            for (int j = 0; j < 8; ++j) { float v = a[i + j]; r[j] = r[j] + v * v; }
        }
        float s = ((r[0] + r[1]) + (r[2] + r[3])) + ((r[4] + r[5]) + (r[6] + r[7]));
        total = (h == 0) ? s : (total + s);
    }
    ee[k] = total;
}

__global__ void a_kernel(const float* __restrict__ z, float* __restrict__ A) {
#pragma clang fp contract(off)
    int n = blockIdx.x * blockDim.x + threadIdx.x;
    int b  = n >> 12;
    int hw = n & (HW - 1);
    const float* base = z + (size_t)b * D_DIM * HW + hw;
    float total = 0.0f;
    #pragma unroll
    for (int h = 0; h < 2; ++h) {
        float r[8];
        #pragma unroll
        for (int j = 0; j < 8; ++j) {
            float v = base[(size_t)(h * 128 + j) * HW];
            r[j] = v * v;
        }
        #pragma unroll
        for (int i = 8; i < 128; i += 8) {
            #pragma unroll
            for (int j = 0; j < 8; ++j) {
                float v = base[(size_t)(h * 128 + i + j) * HW];
                r[j] = r[j] + v * v;
            }
        }
        float s = ((r[0] + r[1]) + (r[2] + r[3])) + ((r[4] + r[5]) + (r[6] + r[7]));
        total = (h == 0) ? s : (total + s);
    }
    A[n] = total;
}

// ---- transpose + fold the exact x2: eT[d][k] = 2*emb[k][d]
// LDS 32x32 tile, both global sides coalesced, +1 pad kills bank conflicts.

__global__ void et_kernel(const float* __restrict__ e, float* __restrict__ eT) {
    __shared__ float t[32][33];
    const int k0 = blockIdx.x * 32;     // 32 tiles over K
    const int d0 = blockIdx.y * 32;     // 8 tiles over D
    const int tx = threadIdx.x;         // 0..31 -> contiguous dim
    const int ty = threadIdx.y;         // 0..7
    #pragma unroll
    for (int i = 0; i < 32; i += 8)
        t[ty + i][tx] = 2.0f * e[(size_t)(k0 + ty + i) * D_DIM + d0 + tx];
    __syncthreads();
    #pragma unroll
    for (int i = 0; i < 32; i += 8)
        eT[(size_t)(d0 + ty + i) * K_DIM + k0 + tx] = t[tx][ty + i];
}

// ---- main: 1 n per thread, e broadcast via SGPRs, 64-k acc tile, no LDS.
// Split s handles k in [s*64, s*64+64); co-resident blocks on a CU share s
// (ids differ by 256 = 0 mod 16) -> same 64KB eT slice in sL1/L2.

__launch_bounds__(256, 5)
__global__ void vq_partial(const float* __restrict__ z, const float* __restrict__ eT,
                           const float* __restrict__ A, const float* __restrict__ ee,
                           unsigned long long* __restrict__ packed) {
#pragma clang fp contract(off)
    const int tid  = threadIdx.x;
    const int s    = blockIdx.x & (NSPLIT - 1);
    const int slab = blockIdx.x >> 4;
    const int n    = slab * 256 + tid;
    const int b    = n >> 12;
    const int hw   = n & (HW - 1);
    const float* __restrict__ zp = z + (size_t)b * D_DIM * HW + hw;
    const int kbase = s * KSPL;

    const float An = A[n];

    float acc[KSPL];
    #pragma unroll
    for (int j = 0; j < KSPL; ++j) acc[j] = 0.0f;

    // z chunk ping-pong: 8 d's per half, prefetched ~1 half ahead.
    // & (D_DIM-1) wrap keeps the last prefetch in-bounds (re-reads d=0..7,
    // unused, L1-hot).
    float za[8], zb[8];
    #pragma unroll
    for (int i = 0; i < 8; ++i) za[i] = zp[(size_t)i * HW];

    #pragma unroll 1
    for (int it = 0; it < 16; ++it) {
        const int base = it * 16;
        // prefetch d = base+8 .. base+15
        #pragma unroll
        for (int i = 0; i < 8; ++i)
            zb[i] = zp[(size_t)((base + 8 + i) & (D_DIM - 1)) * HW];
        // compute d = base .. base+7 (ascending: exact chain)
        #pragma unroll
        for (int dd = 0; dd < 8; ++dd) {
            const float zv = za[dd];
            const float* __restrict__ er = eT + (size_t)(base + dd) * K_DIM + kbase;
            #pragma unroll
            for (int j = 0; j < KSPL; ++j)
                acc[j] = fmaf(zv, er[j], acc[j]);   // er[j] -> SGPR operand
        }
        // prefetch d = base+16 .. base+23 (mod 256)
        #pragma unroll
        for (int i = 0; i < 8; ++i)
            za[i] = zp[(size_t)((base + 16 + i) & (D_DIM - 1)) * HW];
        // compute d = base+8 .. base+15
        #pragma unroll
        for (int dd = 0; dd < 8; ++dd) {
            const float zv = zb[dd];
            const float* __restrict__ er = eT + (size_t)(base + 8 + dd) * K_DIM + kbase;
            #pragma unroll
            for (int j = 0; j < KSPL; ++j)
                acc[j] = fmaf(zv, er[j], acc[j]);
        }
    }

    // epilogue: dist = (An - M2) + ee, k ascending -> first-min ties
    float bestv = F32MAX;
    int   bestk = 0;
    #pragma unroll
    for (int j = 0; j < KSPL; ++j) {
        const float dist = (An - acc[j]) + ee[kbase + j];
        if (dist < bestv) { bestv = dist; bestk = kbase + j; }
    }

    // Order-preserving encode of fp32 (total order, sign-safe), then
    // lexicographic (dist, k) min across splits in one device-scope atomic.
    // Equal dist bits -> lower k wins = reference first-min semantics.
    unsigned int vb = __float_as_uint(bestv);
    vb = (vb & 0x80000000u) ? ~vb : (vb | 0x80000000u);
    const unsigned long long key =
        ((unsigned long long)vb << 32) | (unsigned int)bestk;
    atomicMin(&packed[n], key);
}

__global__ void unpack_kernel(const unsigned long long* __restrict__ packed,
                              int* __restrict__ out) {
    int n = blockIdx.x * blockDim.x + threadIdx.x;
    out[n] = (int)(packed[n] & 0xFFFFFFFFull);
}

extern "C" void kernel_launch(void* const* d_in, const int* in_sizes, int n_in,
                              void* d_out, int out_size, void* d_ws, size_t ws_size,
                              hipStream_t stream) {
    const float* z   = (const float*)d_in[0];   // [16,256,64,64]
    const float* emb = (const float*)d_in[1];   // [1024,256]
    int* out = (int*)d_out;                     // [65536] int32

    float* wsA  = (float*)d_ws;                     // 65536
    float* wsEE = wsA + N_TOT;                      // 1024
    float* wsET = wsEE + K_DIM;                     // 262144
    unsigned long long* wsPacked =
        (unsigned long long*)(wsET + (size_t)D_DIM * K_DIM);  // 65536 u64

    hipMemsetAsync(wsPacked, 0xFF, (size_t)N_TOT * sizeof(unsigned long long),
                   stream);
    et_kernel<<<dim3(K_DIM / 32, D_DIM / 32), dim3(32, 8), 0, stream>>>(emb, wsET);
    ee_kernel<<<K_DIM / 256, 256, 0, stream>>>(emb, wsEE);
    a_kernel<<<N_TOT / 256, 256, 0, stream>>>(z, wsA);
    vq_partial<<<N_TOT / 256 * NSPLIT, 256, 0, stream>>>(z, wsET, wsA, wsEE,
                                                         wsPacked);
    unpack_kernel<<<N_TOT / 256, 256, 0, stream>>>(wsPacked, out);
}